// Round 5
// baseline (212.006 us; speedup 1.0000x reference)
//
#include <hip/hip_runtime.h>
#include <hip/hip_bf16.h>
#include <cstdint>
#include <cstddef>

// Problem constants (B=8, H=12, S=1024, D=64)
#define HH 12
#define BH 96          // B*H
#define SS 1024
#define DD 64
#define KT 64          // keys per KV tile
#define NT (SS / KT)   // 16 tiles
#define QB 128         // q rows per block (2 q-tiles)
#define NQT (SS / QB)  // 8

typedef __attribute__((ext_vector_type(4))) float f32x4;
typedef __attribute__((ext_vector_type(8))) short bf16x8;
typedef __attribute__((ext_vector_type(4))) int   i32x4;
typedef __attribute__((ext_vector_type(2))) unsigned int u32x2;

#define SCL  0.1803368801111204f   // 0.125 * log2(e)  -> exp2 domain
#define NEGL 1442695.0f            // 1e6  * log2(e)

__device__ __forceinline__ unsigned int pk2(float lo, float hi) {
    __hip_bfloat162 h = __float22bfloat162_rn(float2{lo, hi});
    unsigned int u;
    __builtin_memcpy(&u, &h, sizeof(u));   // v_cvt_pk_bf16_f32
    return u;
}

// ---------------------------------------------------------------------------
// Flash attention, f32 in/out, bf16 MFMA, swapped QK^T (P row lane-local).
// Block = 4 waves, 128 q rows. grid = (bh, qt): same-bh blocks share an XCD.
// Double-buffered K/V LDS, 1 barrier/tile; loads for t+1 issued before
// compute(t). XOR-swizzled LDS (elem e of row r at [r][e ^ ((r&7)<<3)]).
// ---------------------------------------------------------------------------
__global__ __launch_bounds__(256, 3) void attn_kernel(
        const float* __restrict__ Q,
        const float* __restrict__ Kb,
        const float* __restrict__ Vb,
        const int* __restrict__ mask,
        float* __restrict__ Out) {
    __shared__ unsigned short Klds[2][KT * DD];   // 16 KB
    __shared__ unsigned short Vlds[2][DD * KT];   // 16 KB
    __shared__ unsigned short Plds[4][16 * KT];   // 8 KB (per-wave)
    __shared__ float Madd[SS];                    // 4 KB

    const int tid  = threadIdx.x;
    const int w    = tid >> 6;
    const int lane = tid & 63;
    const int g    = lane >> 4;
    const int l15  = lane & 15;
    const int swq  = (l15 & 7) << 3;

    const int bh = blockIdx.x;
    const int qt = blockIdx.y;
    const int b  = bh / HH;

    // ---- mask table (once per block, log2 domain) ----
    {
        i32x4 m4 = *(const i32x4*)(mask + b * SS + tid * 4);
        f32x4 a;
#pragma unroll
        for (int j = 0; j < 4; ++j) a[j] = m4[j] ? 0.0f : -NEGL;
        *(f32x4*)&Madd[tid * 4] = a;
    }

    // ---- Q fragments (both 64-row halves), scaled into exp2 domain ----
    bf16x8 qa[2][2];
#pragma unroll
    for (int h = 0; h < 2; ++h) {
        const float* qp = Q + ((size_t)(bh * SS + qt * QB + h * 64 + w * 16 + l15)) * DD + 8 * g;
#pragma unroll
        for (int c = 0; c < 2; ++c) {
            f32x4 lo = *(const f32x4*)(qp + c * 32);
            f32x4 hi = *(const f32x4*)(qp + c * 32 + 4);
            union { bf16x8 v; unsigned int u[4]; } o;
            o.u[0] = pk2(lo[0] * SCL, lo[1] * SCL);
            o.u[1] = pk2(lo[2] * SCL, lo[3] * SCL);
            o.u[2] = pk2(hi[0] * SCL, hi[1] * SCL);
            o.u[3] = pk2(hi[2] * SCL, hi[3] * SCL);
            qa[h][c] = o.v;
        }
    }

    // ---- staging registers ----
    f32x4 kreg[2][2];
    float vreg[2][8];
    auto load_tile_regs = [&](int t) {
#pragma unroll
        for (int i = 0; i < 2; ++i) {
            int c = tid + i * 256;
            {   // K[key][d0..d0+7]
                int row = c >> 3, d0 = (c & 7) * 8;
                const float* kp = Kb + ((size_t)(bh * SS + t * KT + row)) * DD + d0;
                kreg[i][0] = *(const f32x4*)kp;
                kreg[i][1] = *(const f32x4*)(kp + 4);
            }
            {   // V^T gather: 8 keys at fixed d (coalesced across lanes)
                int d = c & 63, k0 = (c >> 6) * 8;
                const float* vp = Vb + ((size_t)(bh * SS + t * KT + k0)) * DD + d;
#pragma unroll
                for (int j = 0; j < 8; ++j) vreg[i][j] = vp[(size_t)j * DD];
            }
        }
    };
    auto write_tile_lds = [&](int pb) {
#pragma unroll
        for (int i = 0; i < 2; ++i) {
            int c = tid + i * 256;
            {
                int row = c >> 3, d0 = (c & 7) * 8;
                union { bf16x8 v; unsigned int u[4]; } kv;
                kv.u[0] = pk2(kreg[i][0][0], kreg[i][0][1]);
                kv.u[1] = pk2(kreg[i][0][2], kreg[i][0][3]);
                kv.u[2] = pk2(kreg[i][1][0], kreg[i][1][1]);
                kv.u[3] = pk2(kreg[i][1][2], kreg[i][1][3]);
                *(bf16x8*)&Klds[pb][row * DD + (d0 ^ ((row & 7) << 3))] = kv.v;
            }
            {
                int d = c & 63, k0 = (c >> 6) * 8;
                union { bf16x8 v; unsigned int u[4]; } vv;
                vv.u[0] = pk2(vreg[i][0], vreg[i][1]);
                vv.u[1] = pk2(vreg[i][2], vreg[i][3]);
                vv.u[2] = pk2(vreg[i][4], vreg[i][5]);
                vv.u[3] = pk2(vreg[i][6], vreg[i][7]);
                *(bf16x8*)&Vlds[pb][d * KT + (k0 ^ ((d & 7) << 3))] = vv.v;
            }
        }
    };

    f32x4 Oacc[2][4];
#pragma unroll
    for (int h = 0; h < 2; ++h)
#pragma unroll
        for (int dt = 0; dt < 4; ++dt) Oacc[h][dt] = (f32x4){0.f, 0.f, 0.f, 0.f};
    float mrow[2] = {-3.0e38f, -3.0e38f};
    float lrow[2] = {0.f, 0.f};

    unsigned short* Pw = &Plds[w][0];

    load_tile_regs(0);
    write_tile_lds(0);
    __syncthreads();

    for (int t = 0; t < NT; ++t) {
        const int pb = t & 1;
        if (t + 1 < NT) load_tile_regs(t + 1);   // issue early; consumed after compute

        f32x4 maddv[4];
#pragma unroll
        for (int n = 0; n < 4; ++n)
            maddv[n] = *(const f32x4*)&Madd[t * KT + 16 * n + 4 * g];

#pragma unroll
        for (int h = 0; h < 2; ++h) {
            // ---- QK^T (swapped): s4[n][r] = S[key=16n+4g+r][q=l15] ----
            f32x4 s4[4];
            __builtin_amdgcn_s_setprio(1);
#pragma unroll
            for (int n = 0; n < 4; ++n) {
                f32x4 acc = (f32x4){0.f, 0.f, 0.f, 0.f};
#pragma unroll
                for (int c = 0; c < 2; ++c) {
                    bf16x8 kb = *(const bf16x8*)
                        &Klds[pb][(16 * n + l15) * DD + ((c * 32 + 8 * g) ^ swq)];
                    acc = __builtin_amdgcn_mfma_f32_16x16x32_bf16(kb, qa[h][c], acc, 0, 0, 0);
                }
                s4[n] = acc + maddv[n];
            }
            __builtin_amdgcn_s_setprio(0);

            // ---- softmax for q=l15: in-lane over 16 scores + 2 shuffles ----
            float tmax;
            {
                f32x4 m4 = s4[0];
#pragma unroll
                for (int n = 1; n < 4; ++n)
#pragma unroll
                    for (int r = 0; r < 4; ++r) m4[r] = fmaxf(m4[r], s4[n][r]);
                tmax = fmaxf(fmaxf(m4[0], m4[1]), fmaxf(m4[2], m4[3]));
            }
            tmax = fmaxf(tmax, __shfl_xor(tmax, 16));
            tmax = fmaxf(tmax, __shfl_xor(tmax, 32));

            float mnew = fmaxf(mrow[h], tmax);
            float corr = __builtin_amdgcn_exp2f(mrow[h] - mnew);
            mrow[h] = mnew;

            float tsum = 0.f;
#pragma unroll
            for (int n = 0; n < 4; ++n)
#pragma unroll
                for (int r = 0; r < 4; ++r) {
                    float pv = __builtin_amdgcn_exp2f(s4[n][r] - mnew);
                    s4[n][r] = pv;
                    tsum += pv;
                }
            tsum += __shfl_xor(tsum, 16);
            tsum += __shfl_xor(tsum, 32);
            lrow[h] = lrow[h] * corr + tsum;

            // rescale Oacc rows (q=4g+r): fetch corr for those q's
            float corrq[4];
#pragma unroll
            for (int r = 0; r < 4; ++r) corrq[r] = __shfl(corr, 4 * g + r);
#pragma unroll
            for (int dt = 0; dt < 4; ++dt)
#pragma unroll
                for (int r = 0; r < 4; ++r) Oacc[h][dt][r] *= corrq[r];

            // ---- P -> LDS: 4 consecutive keys per n-block, b64 writes ----
#pragma unroll
            for (int n = 0; n < 4; ++n) {
                u32x2 pw;
                pw[0] = pk2(s4[n][0], s4[n][1]);
                pw[1] = pk2(s4[n][2], s4[n][3]);
                *(u32x2*)&Pw[l15 * KT + ((16 * n + 4 * g) ^ swq)] = pw;
            }

            // ---- PV ----
            __builtin_amdgcn_s_setprio(1);
#pragma unroll
            for (int ks = 0; ks < 2; ++ks) {
                bf16x8 pa = *(const bf16x8*)&Pw[l15 * KT + ((ks * 32 + 8 * g) ^ swq)];
#pragma unroll
                for (int dt = 0; dt < 4; ++dt) {
                    bf16x8 vb = *(const bf16x8*)
                        &Vlds[pb][(dt * 16 + l15) * KT + ((ks * 32 + 8 * g) ^ swq)];
                    Oacc[h][dt] = __builtin_amdgcn_mfma_f32_16x16x32_bf16(pa, vb, Oacc[h][dt], 0, 0, 0);
                }
            }
            __builtin_amdgcn_s_setprio(0);
        }

        if (t + 1 < NT) {
            write_tile_lds(pb ^ 1);   // waits on the early-issued global loads
            __syncthreads();          // tile t+1 visible; all waves done with t
        }
    }

    // ---- epilogue: O[q=4g+r][d=16dt+l15] /= l(q) ----
#pragma unroll
    for (int h = 0; h < 2; ++h) {
        float inv = 1.0f / lrow[h];
        float invq[4];
#pragma unroll
        for (int r = 0; r < 4; ++r) invq[r] = __shfl(inv, 4 * g + r);
        const size_t rowbase = (size_t)(bh * SS + qt * QB + h * 64 + w * 16);
#pragma unroll
        for (int dt = 0; dt < 4; ++dt)
#pragma unroll
            for (int r = 0; r < 4; ++r)
                Out[(rowbase + 4 * g + r) * DD + dt * 16 + l15] = Oacc[h][dt][r] * invq[r];
    }
}

extern "C" void kernel_launch(void* const* d_in, const int* in_sizes, int n_in,
                              void* d_out, int out_size, void* d_ws, size_t ws_size,
                              hipStream_t stream) {
    const float* Q   = (const float*)d_in[0];
    const float* K   = (const float*)d_in[1];
    const float* V   = (const float*)d_in[2];
    const int* mask  = (const int*)d_in[5];
    float* out       = (float*)d_out;

    attn_kernel<<<dim3(BH, NQT), 256, 0, stream>>>(Q, K, V, mask, out);
}

// Round 6
// 149.066 us; speedup vs baseline: 1.4222x; 1.4222x over previous
//
#include <hip/hip_runtime.h>
#include <hip/hip_bf16.h>
#include <cstdint>
#include <cstddef>

// Problem constants (B=8, H=12, S=1024, D=64)
#define HH 12
#define BH 96          // B*H
#define SS 1024
#define DD 64
#define KT 64          // keys per KV tile
#define NT (SS / KT)   // 16 tiles
#define QB 128         // q rows per block (2 q-tiles)
#define NQT (SS / QB)  // 8

typedef __attribute__((ext_vector_type(4))) float f32x4;
typedef __attribute__((ext_vector_type(8))) short bf16x8;
typedef __attribute__((ext_vector_type(4))) int   i32x4;
typedef __attribute__((ext_vector_type(2))) unsigned int u32x2;

#define SCL  0.1803368801111204f   // 0.125 * log2(e)  -> exp2 domain
#define NEGL 1442695.0f            // 1e6  * log2(e)

__device__ __forceinline__ unsigned int pk2(float lo, float hi) {
    __hip_bfloat162 h = __float22bfloat162_rn(float2{lo, hi});
    unsigned int u;
    __builtin_memcpy(&u, &h, sizeof(u));   // v_cvt_pk_bf16_f32
    return u;
}

// ---------------------------------------------------------------------------
// Flash attention, f32 in/out, bf16 MFMA, swapped QK^T (q-row lane-local
// softmax). Block = 4 waves, 128 q rows. grid = (bh, qt): same-bh blocks
// share an XCD (96 % 8 == 0). Round-4 staging schedule (no spill):
//   barrier; write LDS(t); barrier; issue loads(t+1); compute(t).
// XOR-swizzled LDS (elem e of row r at [r][e ^ ((r&7)<<3)]).
// ---------------------------------------------------------------------------
__global__ __launch_bounds__(256, 3) void attn_kernel(
        const float* __restrict__ Q,
        const float* __restrict__ Kb,
        const float* __restrict__ Vb,
        const int* __restrict__ mask,
        float* __restrict__ Out) {
    __shared__ unsigned short Klds[KT * DD];     // 8 KB
    __shared__ unsigned short Vlds[DD * KT];     // 8 KB
    __shared__ unsigned short Plds[4][16 * KT];  // 8 KB (per-wave)
    __shared__ float Madd[SS];                   // 4 KB

    const int tid  = threadIdx.x;
    const int w    = tid >> 6;
    const int lane = tid & 63;
    const int g    = lane >> 4;
    const int l15  = lane & 15;
    const int swq  = (l15 & 7) << 3;

    const int bh = blockIdx.x;
    const int qt = blockIdx.y;
    const int b  = bh / HH;

    // ---- mask table (once per block, log2 domain) ----
    {
        i32x4 m4 = *(const i32x4*)(mask + b * SS + tid * 4);
        f32x4 a;
#pragma unroll
        for (int j = 0; j < 4; ++j) a[j] = m4[j] ? 0.0f : -NEGL;
        *(f32x4*)&Madd[tid * 4] = a;
    }

    // ---- Q fragments (both 64-row halves), scaled into exp2 domain ----
    bf16x8 qa[2][2];
#pragma unroll
    for (int h = 0; h < 2; ++h) {
        const float* qp = Q + ((size_t)(bh * SS + qt * QB + h * 64 + w * 16 + l15)) * DD + 8 * g;
#pragma unroll
        for (int c = 0; c < 2; ++c) {
            f32x4 lo = *(const f32x4*)(qp + c * 32);
            f32x4 hi = *(const f32x4*)(qp + c * 32 + 4);
            union { bf16x8 v; unsigned int u[4]; } o;
            o.u[0] = pk2(lo[0] * SCL, lo[1] * SCL);
            o.u[1] = pk2(lo[2] * SCL, lo[3] * SCL);
            o.u[2] = pk2(hi[0] * SCL, hi[1] * SCL);
            o.u[3] = pk2(hi[2] * SCL, hi[3] * SCL);
            qa[h][c] = o.v;
        }
    }

    // ---- staging registers ----
    f32x4 kreg[2][2];
    float vreg[2][8];
    auto load_tile_regs = [&](int t) {
#pragma unroll
        for (int i = 0; i < 2; ++i) {
            int c = tid + i * 256;
            {   // K[key][d0..d0+7], coalesced 32B/lane
                int row = c >> 3, d0 = (c & 7) * 8;
                const float* kp = Kb + ((size_t)(bh * SS + t * KT + row)) * DD + d0;
                kreg[i][0] = *(const f32x4*)kp;
                kreg[i][1] = *(const f32x4*)(kp + 4);
            }
            {   // V^T gather: 8 keys at fixed d (d = lane -> coalesced per j)
                int d = c & 63, k0 = (c >> 6) * 8;
                const float* vp = Vb + ((size_t)(bh * SS + t * KT + k0)) * DD + d;
#pragma unroll
                for (int j = 0; j < 8; ++j) vreg[i][j] = vp[(size_t)j * DD];
            }
        }
    };
    auto write_tile_lds = [&]() {
#pragma unroll
        for (int i = 0; i < 2; ++i) {
            int c = tid + i * 256;
            {
                int row = c >> 3, d0 = (c & 7) * 8;
                union { bf16x8 v; unsigned int u[4]; } kv;
                kv.u[0] = pk2(kreg[i][0][0], kreg[i][0][1]);
                kv.u[1] = pk2(kreg[i][0][2], kreg[i][0][3]);
                kv.u[2] = pk2(kreg[i][1][0], kreg[i][1][1]);
                kv.u[3] = pk2(kreg[i][1][2], kreg[i][1][3]);
                *(bf16x8*)&Klds[row * DD + (d0 ^ ((row & 7) << 3))] = kv.v;
            }
            {
                int d = c & 63, k0 = (c >> 6) * 8;
                union { bf16x8 v; unsigned int u[4]; } vv;
                vv.u[0] = pk2(vreg[i][0], vreg[i][1]);
                vv.u[1] = pk2(vreg[i][2], vreg[i][3]);
                vv.u[2] = pk2(vreg[i][4], vreg[i][5]);
                vv.u[3] = pk2(vreg[i][6], vreg[i][7]);
                *(bf16x8*)&Vlds[d * KT + (k0 ^ ((d & 7) << 3))] = vv.v;
            }
        }
    };

    f32x4 Oacc[2][4];
#pragma unroll
    for (int h = 0; h < 2; ++h)
#pragma unroll
        for (int dt = 0; dt < 4; ++dt) Oacc[h][dt] = (f32x4){0.f, 0.f, 0.f, 0.f};
    float mrow[2] = {-3.0e38f, -3.0e38f};
    float lrow[2] = {0.f, 0.f};

    unsigned short* Pw = &Plds[w][0];

    load_tile_regs(0);

    for (int t = 0; t < NT; ++t) {
        __syncthreads();                 // all waves done reading tile t-1
        write_tile_lds();
        __syncthreads();                 // tile t visible
        if (t + 1 < NT) load_tile_regs(t + 1);   // latency hidden under compute(t)

        f32x4 maddv[4];
#pragma unroll
        for (int n = 0; n < 4; ++n)
            maddv[n] = *(const f32x4*)&Madd[t * KT + 16 * n + 4 * g];

#pragma unroll
        for (int h = 0; h < 2; ++h) {
            // ---- QK^T (swapped): s4[n][r] = S[key=16n+4g+r][q=l15] ----
            f32x4 s4[4];
            __builtin_amdgcn_s_setprio(1);
#pragma unroll
            for (int n = 0; n < 4; ++n) {
                f32x4 acc = (f32x4){0.f, 0.f, 0.f, 0.f};
#pragma unroll
                for (int c = 0; c < 2; ++c) {
                    bf16x8 kb = *(const bf16x8*)
                        &Klds[(16 * n + l15) * DD + ((c * 32 + 8 * g) ^ swq)];
                    acc = __builtin_amdgcn_mfma_f32_16x16x32_bf16(kb, qa[h][c], acc, 0, 0, 0);
                }
                s4[n] = acc + maddv[n];
            }
            __builtin_amdgcn_s_setprio(0);

            // ---- softmax for q=l15: in-lane over 16 scores + 2 shuffles ----
            float tmax;
            {
                f32x4 m4 = s4[0];
#pragma unroll
                for (int n = 1; n < 4; ++n)
#pragma unroll
                    for (int r = 0; r < 4; ++r) m4[r] = fmaxf(m4[r], s4[n][r]);
                tmax = fmaxf(fmaxf(m4[0], m4[1]), fmaxf(m4[2], m4[3]));
            }
            tmax = fmaxf(tmax, __shfl_xor(tmax, 16));
            tmax = fmaxf(tmax, __shfl_xor(tmax, 32));

            float mnew = fmaxf(mrow[h], tmax);
            float corr = __builtin_amdgcn_exp2f(mrow[h] - mnew);
            mrow[h] = mnew;

            float tsum = 0.f;
#pragma unroll
            for (int n = 0; n < 4; ++n)
#pragma unroll
                for (int r = 0; r < 4; ++r) {
                    float pv = __builtin_amdgcn_exp2f(s4[n][r] - mnew);
                    s4[n][r] = pv;
                    tsum += pv;
                }
            tsum += __shfl_xor(tsum, 16);
            tsum += __shfl_xor(tsum, 32);
            lrow[h] = lrow[h] * corr + tsum;

            // rescale Oacc rows (q=4g+r): fetch corr for those q's
            float corrq[4];
#pragma unroll
            for (int r = 0; r < 4; ++r) corrq[r] = __shfl(corr, 4 * g + r);
#pragma unroll
            for (int dt = 0; dt < 4; ++dt)
#pragma unroll
                for (int r = 0; r < 4; ++r) Oacc[h][dt][r] *= corrq[r];

            // ---- P -> LDS: P[q=l15][key], 4 consecutive keys per b64 write ----
#pragma unroll
            for (int n = 0; n < 4; ++n) {
                u32x2 pw;
                pw[0] = pk2(s4[n][0], s4[n][1]);
                pw[1] = pk2(s4[n][2], s4[n][3]);
                *(u32x2*)&Pw[l15 * KT + ((16 * n + 4 * g) ^ swq)] = pw;
            }

            // ---- PV ----
            __builtin_amdgcn_s_setprio(1);
#pragma unroll
            for (int ks = 0; ks < 2; ++ks) {
                bf16x8 pa = *(const bf16x8*)&Pw[l15 * KT + ((ks * 32 + 8 * g) ^ swq)];
#pragma unroll
                for (int dt = 0; dt < 4; ++dt) {
                    bf16x8 vb = *(const bf16x8*)
                        &Vlds[(dt * 16 + l15) * KT + ((ks * 32 + 8 * g) ^ swq)];
                    Oacc[h][dt] = __builtin_amdgcn_mfma_f32_16x16x32_bf16(pa, vb, Oacc[h][dt], 0, 0, 0);
                }
            }
            __builtin_amdgcn_s_setprio(0);
        }
    }

    // ---- epilogue: O[q=4g+r][d=16dt+l15] /= l(q) ----
#pragma unroll
    for (int h = 0; h < 2; ++h) {
        float inv = 1.0f / lrow[h];
        float invq[4];
#pragma unroll
        for (int r = 0; r < 4; ++r) invq[r] = __shfl(inv, 4 * g + r);
        const size_t rowbase = (size_t)(bh * SS + qt * QB + h * 64 + w * 16);
#pragma unroll
        for (int dt = 0; dt < 4; ++dt)
#pragma unroll
            for (int r = 0; r < 4; ++r)
                Out[(rowbase + 4 * g + r) * DD + dt * 16 + l15] = Oacc[h][dt][r] * invq[r];
    }
}

extern "C" void kernel_launch(void* const* d_in, const int* in_sizes, int n_in,
                              void* d_out, int out_size, void* d_ws, size_t ws_size,
                              hipStream_t stream) {
    const float* Q   = (const float*)d_in[0];
    const float* K   = (const float*)d_in[1];
    const float* V   = (const float*)d_in[2];
    const int* mask  = (const int*)d_in[5];
    float* out       = (float*)d_out;

    attn_kernel<<<dim3(BH, NQT), 256, 0, stream>>>(Q, K, V, mask, out);
}

// Round 7
// 101.783 us; speedup vs baseline: 2.0829x; 1.4645x over previous
//
#include <hip/hip_runtime.h>
#include <hip/hip_bf16.h>
#include <cstdint>
#include <cstddef>

// Problem constants (B=8, H=12, S=1024, D=64)
#define HH 12
#define BH 96          // B*H
#define SS 1024
#define DD 64
#define KT 64          // keys per KV tile
#define NT (SS / KT)   // 16 tiles
#define QB 64          // q rows per block (1 q-tile of 4 wave-fragments)
#define NQT (SS / QB)  // 16

typedef __attribute__((ext_vector_type(4))) float f32x4;
typedef __attribute__((ext_vector_type(8))) short bf16x8;
typedef __attribute__((ext_vector_type(4))) int   i32x4;

#define SCL  0.1803368801111204f   // 0.125 * log2(e)  -> exp2 domain
#define NEGL 1442695.0f            // 1e6  * log2(e)

__device__ __forceinline__ unsigned int pk2(float lo, float hi) {
    __hip_bfloat162 h = __float22bfloat162_rn(float2{lo, hi});
    unsigned int u;
    __builtin_memcpy(&u, &h, sizeof(u));   // v_cvt_pk_bf16_f32
    return u;
}

// ---------------------------------------------------------------------------
// Flash attention, f32 in/out, bf16 MFMA. Round-4 structure exactly, minus
// the h-loop: block = 4 waves, 64 q rows (16 per wave). grid = (bh, qt),
// 16 qt-blocks of one (b,h) share an XCD (96 % 8 == 0) for K/V L2 reuse.
// Schedule per tile (verified no-spill): barrier; write LDS(t); barrier;
// issue loads(t+1); compute(t). XOR-swizzled LDS ([r][e ^ ((r&7)<<3)]).
// ---------------------------------------------------------------------------
__global__ __launch_bounds__(256, 4) void attn_kernel(
        const float* __restrict__ Q,
        const float* __restrict__ Kb,
        const float* __restrict__ Vb,
        const int* __restrict__ mask,
        float* __restrict__ Out) {
    __shared__ unsigned short Klds[KT * DD];     // 8 KB
    __shared__ unsigned short Vlds[DD * KT];     // 8 KB
    __shared__ unsigned short Plds[4][16 * KT];  // 8 KB (per-wave)
    __shared__ float Madd[SS];                   // 4 KB

    const int tid  = threadIdx.x;
    const int w    = tid >> 6;
    const int lane = tid & 63;
    const int g    = lane >> 4;
    const int l15  = lane & 15;
    const int swq  = (l15 & 7) << 3;

    const int bh = blockIdx.x;
    const int qt = blockIdx.y;
    const int b  = bh / HH;

    // ---- mask table (once per block, log2 domain) ----
    {
        i32x4 m4 = *(const i32x4*)(mask + b * SS + tid * 4);
        f32x4 a;
#pragma unroll
        for (int j = 0; j < 4; ++j) a[j] = m4[j] ? 0.0f : -NEGL;
        *(f32x4*)&Madd[tid * 4] = a;
    }

    // ---- Q fragments, scaled into exp2 domain ----
    bf16x8 qa[2];
    {
        const float* qp = Q + ((size_t)(bh * SS + qt * QB + w * 16 + l15)) * DD + 8 * g;
#pragma unroll
        for (int c = 0; c < 2; ++c) {
            f32x4 lo = *(const f32x4*)(qp + c * 32);
            f32x4 hi = *(const f32x4*)(qp + c * 32 + 4);
            union { bf16x8 v; unsigned int u[4]; } o;
            o.u[0] = pk2(lo[0] * SCL, lo[1] * SCL);
            o.u[1] = pk2(lo[2] * SCL, lo[3] * SCL);
            o.u[2] = pk2(hi[0] * SCL, hi[1] * SCL);
            o.u[3] = pk2(hi[2] * SCL, hi[3] * SCL);
            qa[c] = o.v;
        }
    }

    // ---- staging registers ----
    f32x4 kreg[2][2];
    float vreg[2][8];
    auto load_tile_regs = [&](int t) {
#pragma unroll
        for (int i = 0; i < 2; ++i) {
            int c = tid + i * 256;
            {   // K[key][d0..d0+7], coalesced 32B/lane
                int row = c >> 3, d0 = (c & 7) * 8;
                const float* kp = Kb + ((size_t)(bh * SS + t * KT + row)) * DD + d0;
                kreg[i][0] = *(const f32x4*)kp;
                kreg[i][1] = *(const f32x4*)(kp + 4);
            }
            {   // V^T gather: 8 keys at fixed d (d = lane -> coalesced per j)
                int d = c & 63, k0 = (c >> 6) * 8;
                const float* vp = Vb + ((size_t)(bh * SS + t * KT + k0)) * DD + d;
#pragma unroll
                for (int j = 0; j < 8; ++j) vreg[i][j] = vp[(size_t)j * DD];
            }
        }
    };
    auto write_tile_lds = [&]() {
#pragma unroll
        for (int i = 0; i < 2; ++i) {
            int c = tid + i * 256;
            {
                int row = c >> 3, d0 = (c & 7) * 8;
                union { bf16x8 v; unsigned int u[4]; } kv;
                kv.u[0] = pk2(kreg[i][0][0], kreg[i][0][1]);
                kv.u[1] = pk2(kreg[i][0][2], kreg[i][0][3]);
                kv.u[2] = pk2(kreg[i][1][0], kreg[i][1][1]);
                kv.u[3] = pk2(kreg[i][1][2], kreg[i][1][3]);
                *(bf16x8*)&Klds[row * DD + (d0 ^ ((row & 7) << 3))] = kv.v;
            }
            {
                int d = c & 63, k0 = (c >> 6) * 8;
                union { bf16x8 v; unsigned int u[4]; } vv;
                vv.u[0] = pk2(vreg[i][0], vreg[i][1]);
                vv.u[1] = pk2(vreg[i][2], vreg[i][3]);
                vv.u[2] = pk2(vreg[i][4], vreg[i][5]);
                vv.u[3] = pk2(vreg[i][6], vreg[i][7]);
                *(bf16x8*)&Vlds[d * KT + (k0 ^ ((d & 7) << 3))] = vv.v;
            }
        }
    };

    f32x4 Oacc[4];
#pragma unroll
    for (int dt = 0; dt < 4; ++dt) Oacc[dt] = (f32x4){0.f, 0.f, 0.f, 0.f};
    float mrow[4], lrow[4];
#pragma unroll
    for (int r = 0; r < 4; ++r) { mrow[r] = -3.0e38f; lrow[r] = 0.f; }

    unsigned short* Pw = &Plds[w][0];

    load_tile_regs(0);

    for (int t = 0; t < NT; ++t) {
        __syncthreads();                 // all waves done reading tile t-1
        write_tile_lds();
        __syncthreads();                 // tile t visible
        if (t + 1 < NT) load_tile_regs(t + 1);   // latency hidden under compute(t)

        float madd[4];
#pragma unroll
        for (int n = 0; n < 4; ++n) madd[n] = Madd[t * KT + 16 * n + l15];

        // ---- QK^T: s4[n][r] = score[q=4g+r][key=16n+l15] (log2 domain) ----
        f32x4 s4[4];
        __builtin_amdgcn_s_setprio(1);
#pragma unroll
        for (int n = 0; n < 4; ++n) {
            f32x4 acc = (f32x4){0.f, 0.f, 0.f, 0.f};
#pragma unroll
            for (int c = 0; c < 2; ++c) {
                bf16x8 kb = *(const bf16x8*)
                    &Klds[(16 * n + l15) * DD + ((c * 32 + 8 * g) ^ swq)];
                acc = __builtin_amdgcn_mfma_f32_16x16x32_bf16(qa[c], kb, acc, 0, 0, 0);
            }
#pragma unroll
            for (int r = 0; r < 4; ++r) s4[n][r] = acc[r] + madd[n];
        }
        __builtin_amdgcn_s_setprio(0);

        // ---- online softmax (row q=4g+r on the 16 lanes of group g) ----
        float tmax[4];
#pragma unroll
        for (int r = 0; r < 4; ++r)
            tmax[r] = fmaxf(fmaxf(s4[0][r], s4[1][r]), fmaxf(s4[2][r], s4[3][r]));
#pragma unroll
        for (int r = 0; r < 4; ++r)
#pragma unroll
            for (int msk = 1; msk < 16; msk <<= 1)
                tmax[r] = fmaxf(tmax[r], __shfl_xor(tmax[r], msk));

        float corr[4], tsum[4];
#pragma unroll
        for (int r = 0; r < 4; ++r) {
            float mnew = fmaxf(mrow[r], tmax[r]);
            corr[r] = exp2f(mrow[r] - mnew);
            mrow[r] = mnew;
            tsum[r] = 0.f;
        }
        // p = exp2(s - m), accumulate sum, write bf16 P to LDS (swizzled)
#pragma unroll
        for (int n = 0; n < 4; ++n) {
            int key = 16 * n + l15;
            float pv[4];
#pragma unroll
            for (int r = 0; r < 4; ++r) {
                pv[r] = exp2f(s4[n][r] - mrow[r]);
                tsum[r] += pv[r];
            }
            unsigned int w01 = pk2(pv[0], pv[1]);
            unsigned int w23 = pk2(pv[2], pv[3]);
            Plds[w][(4 * g + 0) * KT + (key ^ (((4 * g + 0) & 7) << 3))] = (unsigned short)(w01 & 0xffff);
            Plds[w][(4 * g + 1) * KT + (key ^ (((4 * g + 1) & 7) << 3))] = (unsigned short)(w01 >> 16);
            Plds[w][(4 * g + 2) * KT + (key ^ (((4 * g + 2) & 7) << 3))] = (unsigned short)(w23 & 0xffff);
            Plds[w][(4 * g + 3) * KT + (key ^ (((4 * g + 3) & 7) << 3))] = (unsigned short)(w23 >> 16);
        }
#pragma unroll
        for (int r = 0; r < 4; ++r) {
#pragma unroll
            for (int msk = 1; msk < 16; msk <<= 1)
                tsum[r] += __shfl_xor(tsum[r], msk);
            lrow[r] = lrow[r] * corr[r] + tsum[r];
        }
#pragma unroll
        for (int dt = 0; dt < 4; ++dt)
#pragma unroll
            for (int r = 0; r < 4; ++r) Oacc[dt][r] *= corr[r];

        // ---- PV ----
        __builtin_amdgcn_s_setprio(1);
#pragma unroll
        for (int ks = 0; ks < 2; ++ks) {
            bf16x8 pa = *(const bf16x8*)&Pw[l15 * KT + ((ks * 32 + 8 * g) ^ swq)];
#pragma unroll
            for (int dt = 0; dt < 4; ++dt) {
                bf16x8 vb = *(const bf16x8*)
                    &Vlds[(dt * 16 + l15) * KT + ((ks * 32 + 8 * g) ^ swq)];
                Oacc[dt] = __builtin_amdgcn_mfma_f32_16x16x32_bf16(pa, vb, Oacc[dt], 0, 0, 0);
            }
        }
        __builtin_amdgcn_s_setprio(0);
    }

    // ---- epilogue: O[q=4g+r][d=16dt+l15] /= l(q) ----
    float inv[4];
#pragma unroll
    for (int r = 0; r < 4; ++r) inv[r] = 1.0f / lrow[r];
    const size_t rowbase = (size_t)(bh * SS + qt * QB + w * 16);
#pragma unroll
    for (int dt = 0; dt < 4; ++dt)
#pragma unroll
        for (int r = 0; r < 4; ++r)
            Out[(rowbase + 4 * g + r) * DD + dt * 16 + l15] = Oacc[dt][r] * inv[r];
}

extern "C" void kernel_launch(void* const* d_in, const int* in_sizes, int n_in,
                              void* d_out, int out_size, void* d_ws, size_t ws_size,
                              hipStream_t stream) {
    const float* Q   = (const float*)d_in[0];
    const float* K   = (const float*)d_in[1];
    const float* V   = (const float*)d_in[2];
    const int* mask  = (const int*)d_in[5];
    float* out       = (float*)d_out;

    attn_kernel<<<dim3(BH, NQT), 256, 0, stream>>>(Q, K, V, mask, out);
}

// Round 8
// 82.528 us; speedup vs baseline: 2.5689x; 1.2333x over previous
//
#include <hip/hip_runtime.h>
#include <hip/hip_bf16.h>
#include <cstdint>
#include <cstddef>

// Problem constants (B=8, H=12, S=1024, D=64)
#define HH 12
#define BH 96          // B*H
#define SS 1024
#define DD 64
#define KT 64          // keys per KV tile
#define NT (SS / KT)   // 16 tiles
#define QB 64          // q rows per block (16 per wave)
#define NQT (SS / QB)  // 16

typedef __attribute__((ext_vector_type(4))) float f32x4;
typedef __attribute__((ext_vector_type(8))) short bf16x8;
typedef __attribute__((ext_vector_type(4))) int   i32x4;

#define SCL  0.1803368801111204f   // 0.125 * log2(e)  -> exp2 domain
#define NEGL 1442695.0f            // 1e6  * log2(e)

__device__ __forceinline__ unsigned int pk2(float lo, float hi) {
    __hip_bfloat162 h = __float22bfloat162_rn(float2{lo, hi});
    unsigned int u;
    __builtin_memcpy(&u, &h, sizeof(u));   // v_cvt_pk_bf16_f32
    return u;
}

// ---------------------------------------------------------------------------
// Flash attention, f32 in/out, bf16 MFMA, swapped QK^T (q-row lane-local),
// P kept fully IN REGISTER: permlane32_swap + ds_swizzle(xor16) rebuild the
// PV A-fragment without any P LDS traffic. Block = 4 waves, 64 q rows.
// grid = (bh, qt): same-bh blocks share an XCD (96 % 8 == 0).
// Schedule per tile (verified no-spill): barrier; write LDS(t); barrier;
// issue loads(t+1); compute(t). K/V LDS XOR-swizzled ([r][e ^ ((r&7)<<3)]).
// ---------------------------------------------------------------------------
__global__ __launch_bounds__(256, 4) void attn_kernel(
        const float* __restrict__ Q,
        const float* __restrict__ Kb,
        const float* __restrict__ Vb,
        const int* __restrict__ mask,
        float* __restrict__ Out) {
    __shared__ unsigned short Klds[KT * DD];     // 8 KB
    __shared__ unsigned short Vlds[DD * KT];     // 8 KB
    __shared__ float Madd[SS];                   // 4 KB (log2-domain mask add)

    const int tid  = threadIdx.x;
    const int w    = tid >> 6;
    const int lane = tid & 63;
    const int g    = lane >> 4;
    const int l15  = lane & 15;
    const int swq  = (l15 & 7) << 3;

    const int bh = blockIdx.x;
    const int qt = blockIdx.y;
    const int b  = bh / HH;

    // ---- mask table (once per block, log2 domain) ----
    {
        i32x4 m4 = *(const i32x4*)(mask + b * SS + tid * 4);
        f32x4 a;
#pragma unroll
        for (int j = 0; j < 4; ++j) a[j] = m4[j] ? 0.0f : -NEGL;
        *(f32x4*)&Madd[tid * 4] = a;
    }

    // ---- Q fragments (B-operand of swapped QK^T), scaled, exp2 domain ----
    bf16x8 qa[2];
    {
        const float* qp = Q + ((size_t)(bh * SS + qt * QB + w * 16 + l15)) * DD + 8 * g;
#pragma unroll
        for (int c = 0; c < 2; ++c) {
            f32x4 lo = *(const f32x4*)(qp + c * 32);
            f32x4 hi = *(const f32x4*)(qp + c * 32 + 4);
            union { bf16x8 v; unsigned int u[4]; } o;
            o.u[0] = pk2(lo[0] * SCL, lo[1] * SCL);
            o.u[1] = pk2(lo[2] * SCL, lo[3] * SCL);
            o.u[2] = pk2(hi[0] * SCL, hi[1] * SCL);
            o.u[3] = pk2(hi[2] * SCL, hi[3] * SCL);
            qa[c] = o.v;
        }
    }

    // ---- staging registers (round-7 verified path) ----
    f32x4 kreg[2][2];
    float vreg[2][8];
    auto load_tile_regs = [&](int t) {
#pragma unroll
        for (int i = 0; i < 2; ++i) {
            int c = tid + i * 256;
            {   // K[key][d0..d0+7], coalesced 32B/lane
                int row = c >> 3, d0 = (c & 7) * 8;
                const float* kp = Kb + ((size_t)(bh * SS + t * KT + row)) * DD + d0;
                kreg[i][0] = *(const f32x4*)kp;
                kreg[i][1] = *(const f32x4*)(kp + 4);
            }
            {   // V^T gather: 8 keys at fixed d (d = lane -> coalesced per j)
                int d = c & 63, k0 = (c >> 6) * 8;
                const float* vp = Vb + ((size_t)(bh * SS + t * KT + k0)) * DD + d;
#pragma unroll
                for (int j = 0; j < 8; ++j) vreg[i][j] = vp[(size_t)j * DD];
            }
        }
    };
    auto write_tile_lds = [&]() {
#pragma unroll
        for (int i = 0; i < 2; ++i) {
            int c = tid + i * 256;
            {
                int row = c >> 3, d0 = (c & 7) * 8;
                union { bf16x8 v; unsigned int u[4]; } kv;
                kv.u[0] = pk2(kreg[i][0][0], kreg[i][0][1]);
                kv.u[1] = pk2(kreg[i][0][2], kreg[i][0][3]);
                kv.u[2] = pk2(kreg[i][1][0], kreg[i][1][1]);
                kv.u[3] = pk2(kreg[i][1][2], kreg[i][1][3]);
                *(bf16x8*)&Klds[row * DD + (d0 ^ ((row & 7) << 3))] = kv.v;
            }
            {
                int d = c & 63, k0 = (c >> 6) * 8;
                union { bf16x8 v; unsigned int u[4]; } vv;
                vv.u[0] = pk2(vreg[i][0], vreg[i][1]);
                vv.u[1] = pk2(vreg[i][2], vreg[i][3]);
                vv.u[2] = pk2(vreg[i][4], vreg[i][5]);
                vv.u[3] = pk2(vreg[i][6], vreg[i][7]);
                *(bf16x8*)&Vlds[d * KT + (k0 ^ ((d & 7) << 3))] = vv.v;
            }
        }
    };

    f32x4 Oacc[4];
#pragma unroll
    for (int dt = 0; dt < 4; ++dt) Oacc[dt] = (f32x4){0.f, 0.f, 0.f, 0.f};
    float mrow = -3.0e38f;     // running max for q = l15 (uniform across g)
    float lrow = 0.f;

    load_tile_regs(0);

    for (int t = 0; t < NT; ++t) {
        __syncthreads();                 // all waves done reading tile t-1
        write_tile_lds();
        __syncthreads();                 // tile t visible
        if (t + 1 < NT) load_tile_regs(t + 1);   // latency hidden under compute(t)

        // ---- QK^T (swapped): s4[n][r] = S[key=16n+4g+r][q=l15] ----
        f32x4 s4[4];
        __builtin_amdgcn_s_setprio(1);
#pragma unroll
        for (int n = 0; n < 4; ++n) {
            f32x4 acc = (f32x4){0.f, 0.f, 0.f, 0.f};
#pragma unroll
            for (int c = 0; c < 2; ++c) {
                bf16x8 kb = *(const bf16x8*)
                    &Klds[(16 * n + l15) * DD + ((c * 32 + 8 * g) ^ swq)];
                acc = __builtin_amdgcn_mfma_f32_16x16x32_bf16(kb, qa[c], acc, 0, 0, 0);
            }
            const float* mp = &Madd[t * KT + 16 * n + 4 * g];
#pragma unroll
            for (int r = 0; r < 4; ++r) s4[n][r] = acc[r] + mp[r];
        }
        __builtin_amdgcn_s_setprio(0);

        // ---- softmax for q=l15: 15 in-lane fmax + 2 shuffles ----
        float tmax;
        {
            f32x4 m4 = s4[0];
#pragma unroll
            for (int n = 1; n < 4; ++n)
#pragma unroll
                for (int r = 0; r < 4; ++r) m4[r] = fmaxf(m4[r], s4[n][r]);
            tmax = fmaxf(fmaxf(m4[0], m4[1]), fmaxf(m4[2], m4[3]));
        }
        tmax = fmaxf(tmax, __shfl_xor(tmax, 16));
        tmax = fmaxf(tmax, __shfl_xor(tmax, 32));

        float mnew = fmaxf(mrow, tmax);
        float corr = exp2f(mrow - mnew);
        mrow = mnew;

        float tsum = 0.f;
        unsigned int pks[4][2];          // bf16-packed P, static-indexed only
#pragma unroll
        for (int n = 0; n < 4; ++n) {
            float p0 = exp2f(s4[n][0] - mnew);
            float p1 = exp2f(s4[n][1] - mnew);
            float p2 = exp2f(s4[n][2] - mnew);
            float p3 = exp2f(s4[n][3] - mnew);
            tsum += (p0 + p1) + (p2 + p3);
            pks[n][0] = pk2(p0, p1);
            pks[n][1] = pk2(p2, p3);
        }
        tsum += __shfl_xor(tsum, 16);
        tsum += __shfl_xor(tsum, 32);
        lrow = lrow * corr + tsum;

        // rescale Oacc rows (q=4g+r): corr for q' lives at lane l15'=q'
        float corrq[4];
#pragma unroll
        for (int r = 0; r < 4; ++r) corrq[r] = __shfl(corr, 4 * g + r);
#pragma unroll
        for (int dt = 0; dt < 4; ++dt)
#pragma unroll
            for (int r = 0; r < 4; ++r) Oacc[dt][r] *= corrq[r];

        // ---- PV with in-register A-fragment (permlane32_swap + swz16) ----
        __builtin_amdgcn_s_setprio(1);
        const bool odd = (g & 1);
#pragma unroll
        for (int ks = 0; ks < 2; ++ks) {
            // (Sx,Sy) = [Plo|Qlo],[Phi|Qhi] across the two 32-lane halves
            auto sw0 = __builtin_amdgcn_permlane32_swap(pks[2 * ks][0], pks[2 * ks + 1][0], false, false);
            auto sw1 = __builtin_amdgcn_permlane32_swap(pks[2 * ks][1], pks[2 * ks + 1][1], false, false);
            unsigned int S0x = sw0[0], S0y = sw0[1];
            unsigned int S1x = sw1[0], S1y = sw1[1];
            unsigned int T0 = (unsigned int)__builtin_amdgcn_ds_swizzle((int)S0y, 0x401F); // lane^16
            unsigned int U0 = (unsigned int)__builtin_amdgcn_ds_swizzle((int)S0x, 0x401F);
            unsigned int T1 = (unsigned int)__builtin_amdgcn_ds_swizzle((int)S1y, 0x401F);
            unsigned int U1 = (unsigned int)__builtin_amdgcn_ds_swizzle((int)S1x, 0x401F);
            union { bf16x8 v; unsigned int u[4]; } pa;
            pa.u[0] = odd ? T0 : S0x;    // P[q=l15][k=8g+0,1] within 32-key block
            pa.u[1] = odd ? T1 : S1x;    // k=8g+2,3
            pa.u[2] = odd ? S0y : U0;    // k=8g+4,5
            pa.u[3] = odd ? S1y : U1;    // k=8g+6,7
#pragma unroll
            for (int dt = 0; dt < 4; ++dt) {
                bf16x8 vb = *(const bf16x8*)
                    &Vlds[(dt * 16 + l15) * KT + ((ks * 32 + 8 * g) ^ swq)];
                Oacc[dt] = __builtin_amdgcn_mfma_f32_16x16x32_bf16(pa.v, vb, Oacc[dt], 0, 0, 0);
            }
        }
        __builtin_amdgcn_s_setprio(0);
    }

    // ---- epilogue: O[q=4g+r][d=16dt+l15] /= l(q) ----
    float inv = 1.0f / lrow;
    float invq[4];
#pragma unroll
    for (int r = 0; r < 4; ++r) invq[r] = __shfl(inv, 4 * g + r);
    const size_t rowbase = (size_t)(bh * SS + qt * QB + w * 16);
#pragma unroll
    for (int dt = 0; dt < 4; ++dt)
#pragma unroll
        for (int r = 0; r < 4; ++r)
            Out[(rowbase + 4 * g + r) * DD + dt * 16 + l15] = Oacc[dt][r] * invq[r];
}

extern "C" void kernel_launch(void* const* d_in, const int* in_sizes, int n_in,
                              void* d_out, int out_size, void* d_ws, size_t ws_size,
                              hipStream_t stream) {
    const float* Q   = (const float*)d_in[0];
    const float* K   = (const float*)d_in[1];
    const float* V   = (const float*)d_in[2];
    const int* mask  = (const int*)d_in[5];
    float* out       = (float*)d_out;

    attn_kernel<<<dim3(BH, NQT), 256, 0, stream>>>(Q, K, V, mask, out);
}

// Round 9
// 69.855 us; speedup vs baseline: 3.0350x; 1.1814x over previous
//
#include <hip/hip_runtime.h>
#include <hip/hip_bf16.h>
#include <cstdint>
#include <cstddef>

// Problem constants (B=8, H=12, S=1024, D=64)
#define HH 12
#define BH 96          // B*H
#define SS 1024
#define DD 64
#define KT 64          // keys per KV tile
#define NT (SS / KT)   // 16 tiles
#define QB 64          // q rows per block (16 per wave)
#define NQT (SS / QB)  // 16

typedef __attribute__((ext_vector_type(4))) float f32x4;
typedef __attribute__((ext_vector_type(8))) short bf16x8;
typedef __attribute__((ext_vector_type(4))) int   i32x4;

#define SCL  0.1803368801111204f   // 0.125 * log2(e)  -> exp2 domain
#define NEGL 1442695.0f            // 1e6  * log2(e)
#define THR  8.0f                  // defer-max threshold (log2 domain)

__device__ __forceinline__ unsigned int pk2(float lo, float hi) {
    __hip_bfloat162 h = __float22bfloat162_rn(float2{lo, hi});
    unsigned int u;
    __builtin_memcpy(&u, &h, sizeof(u));   // v_cvt_pk_bf16_f32
    return u;
}

// ---------------------------------------------------------------------------
// Flash attention, f32 in/out, bf16 MFMA, swapped QK^T (q-row lane-local),
// P fully in-register (permlane32_swap + ds_swizzle xor16). Mask folded into
// the MFMA C-initializer. Raw v_exp_f32 via builtin. Defer-max (THR=8,
// log2 domain) skips the O-rescale on most tiles. Block = 4 waves, 64 q
// rows; grid = (bh, qt): same-bh blocks share an XCD (96 % 8 == 0).
// Schedule per tile (verified no-spill): barrier; write LDS(t); barrier;
// issue loads(t+1); compute(t). K/V LDS XOR-swizzled ([r][e ^ ((r&7)<<3)]).
// ---------------------------------------------------------------------------
__global__ __launch_bounds__(256, 4) void attn_kernel(
        const float* __restrict__ Q,
        const float* __restrict__ Kb,
        const float* __restrict__ Vb,
        const int* __restrict__ mask,
        float* __restrict__ Out) {
    __shared__ unsigned short Klds[KT * DD];     // 8 KB
    __shared__ unsigned short Vlds[DD * KT];     // 8 KB
    __shared__ float Madd[SS];                   // 4 KB (log2-domain mask add)

    const int tid  = threadIdx.x;
    const int w    = tid >> 6;
    const int lane = tid & 63;
    const int g    = lane >> 4;
    const int l15  = lane & 15;
    const int swq  = (l15 & 7) << 3;

    const int bh = blockIdx.x;
    const int qt = blockIdx.y;
    const int b  = bh / HH;

    // ---- mask table (once per block, log2 domain) ----
    {
        i32x4 m4 = *(const i32x4*)(mask + b * SS + tid * 4);
        f32x4 a;
#pragma unroll
        for (int j = 0; j < 4; ++j) a[j] = m4[j] ? 0.0f : -NEGL;
        *(f32x4*)&Madd[tid * 4] = a;
    }

    // ---- Q fragments (B-operand of swapped QK^T), scaled, exp2 domain ----
    bf16x8 qa[2];
    {
        const float* qp = Q + ((size_t)(bh * SS + qt * QB + w * 16 + l15)) * DD + 8 * g;
#pragma unroll
        for (int c = 0; c < 2; ++c) {
            f32x4 lo = *(const f32x4*)(qp + c * 32);
            f32x4 hi = *(const f32x4*)(qp + c * 32 + 4);
            union { bf16x8 v; unsigned int u[4]; } o;
            o.u[0] = pk2(lo[0] * SCL, lo[1] * SCL);
            o.u[1] = pk2(lo[2] * SCL, lo[3] * SCL);
            o.u[2] = pk2(hi[0] * SCL, hi[1] * SCL);
            o.u[3] = pk2(hi[2] * SCL, hi[3] * SCL);
            qa[c] = o.v;
        }
    }

    // ---- staging registers (round-7/8 verified path) ----
    f32x4 kreg[2][2];
    float vreg[2][8];
    auto load_tile_regs = [&](int t) {
#pragma unroll
        for (int i = 0; i < 2; ++i) {
            int c = tid + i * 256;
            {   // K[key][d0..d0+7], coalesced 32B/lane
                int row = c >> 3, d0 = (c & 7) * 8;
                const float* kp = Kb + ((size_t)(bh * SS + t * KT + row)) * DD + d0;
                kreg[i][0] = *(const f32x4*)kp;
                kreg[i][1] = *(const f32x4*)(kp + 4);
            }
            {   // V^T gather: 8 keys at fixed d (d = lane -> coalesced per j)
                int d = c & 63, k0 = (c >> 6) * 8;
                const float* vp = Vb + ((size_t)(bh * SS + t * KT + k0)) * DD + d;
#pragma unroll
                for (int j = 0; j < 8; ++j) vreg[i][j] = vp[(size_t)j * DD];
            }
        }
    };
    auto write_tile_lds = [&]() {
#pragma unroll
        for (int i = 0; i < 2; ++i) {
            int c = tid + i * 256;
            {
                int row = c >> 3, d0 = (c & 7) * 8;
                union { bf16x8 v; unsigned int u[4]; } kv;
                kv.u[0] = pk2(kreg[i][0][0], kreg[i][0][1]);
                kv.u[1] = pk2(kreg[i][0][2], kreg[i][0][3]);
                kv.u[2] = pk2(kreg[i][1][0], kreg[i][1][1]);
                kv.u[3] = pk2(kreg[i][1][2], kreg[i][1][3]);
                *(bf16x8*)&Klds[row * DD + (d0 ^ ((row & 7) << 3))] = kv.v;
            }
            {
                int d = c & 63, k0 = (c >> 6) * 8;
                union { bf16x8 v; unsigned int u[4]; } vv;
                vv.u[0] = pk2(vreg[i][0], vreg[i][1]);
                vv.u[1] = pk2(vreg[i][2], vreg[i][3]);
                vv.u[2] = pk2(vreg[i][4], vreg[i][5]);
                vv.u[3] = pk2(vreg[i][6], vreg[i][7]);
                *(bf16x8*)&Vlds[d * KT + (k0 ^ ((d & 7) << 3))] = vv.v;
            }
        }
    };

    f32x4 Oacc[4];
#pragma unroll
    for (int dt = 0; dt < 4; ++dt) Oacc[dt] = (f32x4){0.f, 0.f, 0.f, 0.f};
    float mrow = -3.0e38f;     // running max for q = l15 (uniform across g)
    float lrow = 0.f;

    load_tile_regs(0);

    for (int t = 0; t < NT; ++t) {
        __syncthreads();                 // all waves done reading tile t-1
        write_tile_lds();
        __syncthreads();                 // tile t visible
        if (t + 1 < NT) load_tile_regs(t + 1);   // latency hidden under compute(t)

        // ---- QK^T (swapped): s4[n][r] = S[key=16n+4g+r][q=l15] ----
        // mask folded into the MFMA C-initializer (D = A·B + C)
        f32x4 s4[4];
        __builtin_amdgcn_s_setprio(1);
#pragma unroll
        for (int n = 0; n < 4; ++n) {
            f32x4 acc = *(const f32x4*)&Madd[t * KT + 16 * n + 4 * g];
#pragma unroll
            for (int c = 0; c < 2; ++c) {
                bf16x8 kb = *(const bf16x8*)
                    &Klds[(16 * n + l15) * DD + ((c * 32 + 8 * g) ^ swq)];
                acc = __builtin_amdgcn_mfma_f32_16x16x32_bf16(kb, qa[c], acc, 0, 0, 0);
            }
            s4[n] = acc;
        }
        __builtin_amdgcn_s_setprio(0);

        // ---- softmax for q=l15: 15 in-lane fmax + 2 shuffles ----
        float tmax;
        {
            f32x4 m4 = s4[0];
#pragma unroll
            for (int n = 1; n < 4; ++n)
#pragma unroll
                for (int r = 0; r < 4; ++r) m4[r] = fmaxf(m4[r], s4[n][r]);
            tmax = fmaxf(fmaxf(m4[0], m4[1]), fmaxf(m4[2], m4[3]));
        }
        tmax = fmaxf(tmax, __shfl_xor(tmax, 16));
        tmax = fmaxf(tmax, __shfl_xor(tmax, 32));

        // ---- defer-max (T13): rescale only when max grew past THR ----
        if (!__all(tmax <= mrow + THR)) {
            float mnew = fmaxf(mrow, tmax);
            float corr = __builtin_amdgcn_exp2f(mrow - mnew);
            mrow = mnew;
            lrow *= corr;
            float corrq[4];
#pragma unroll
            for (int r = 0; r < 4; ++r) corrq[r] = __shfl(corr, 4 * g + r);
#pragma unroll
            for (int dt = 0; dt < 4; ++dt)
#pragma unroll
                for (int r = 0; r < 4; ++r) Oacc[dt][r] *= corrq[r];
        }

        float tsum = 0.f;
        unsigned int pks[4][2];          // bf16-packed P, static-indexed only
#pragma unroll
        for (int n = 0; n < 4; ++n) {
            float p0 = __builtin_amdgcn_exp2f(s4[n][0] - mrow);
            float p1 = __builtin_amdgcn_exp2f(s4[n][1] - mrow);
            float p2 = __builtin_amdgcn_exp2f(s4[n][2] - mrow);
            float p3 = __builtin_amdgcn_exp2f(s4[n][3] - mrow);
            tsum += (p0 + p1) + (p2 + p3);
            pks[n][0] = pk2(p0, p1);
            pks[n][1] = pk2(p2, p3);
        }
        tsum += __shfl_xor(tsum, 16);
        tsum += __shfl_xor(tsum, 32);
        lrow += tsum;

        // ---- PV with in-register A-fragment (permlane32_swap + swz16) ----
        __builtin_amdgcn_s_setprio(1);
        const bool odd = (g & 1);
#pragma unroll
        for (int ks = 0; ks < 2; ++ks) {
            auto sw0 = __builtin_amdgcn_permlane32_swap(pks[2 * ks][0], pks[2 * ks + 1][0], false, false);
            auto sw1 = __builtin_amdgcn_permlane32_swap(pks[2 * ks][1], pks[2 * ks + 1][1], false, false);
            unsigned int S0x = sw0[0], S0y = sw0[1];
            unsigned int S1x = sw1[0], S1y = sw1[1];
            unsigned int T0 = (unsigned int)__builtin_amdgcn_ds_swizzle((int)S0y, 0x401F); // lane^16
            unsigned int U0 = (unsigned int)__builtin_amdgcn_ds_swizzle((int)S0x, 0x401F);
            unsigned int T1 = (unsigned int)__builtin_amdgcn_ds_swizzle((int)S1y, 0x401F);
            unsigned int U1 = (unsigned int)__builtin_amdgcn_ds_swizzle((int)S1x, 0x401F);
            union { bf16x8 v; unsigned int u[4]; } pa;
            pa.u[0] = odd ? T0 : S0x;    // P[q=l15][k=8g+0,1] within 32-key block
            pa.u[1] = odd ? T1 : S1x;    // k=8g+2,3
            pa.u[2] = odd ? S0y : U0;    // k=8g+4,5
            pa.u[3] = odd ? S1y : U1;    // k=8g+6,7
#pragma unroll
            for (int dt = 0; dt < 4; ++dt) {
                bf16x8 vb = *(const bf16x8*)
                    &Vlds[(dt * 16 + l15) * KT + ((ks * 32 + 8 * g) ^ swq)];
                Oacc[dt] = __builtin_amdgcn_mfma_f32_16x16x32_bf16(pa.v, vb, Oacc[dt], 0, 0, 0);
            }
        }
        __builtin_amdgcn_s_setprio(0);
    }

    // ---- epilogue: O[q=4g+r][d=16dt+l15] /= l(q) ----
    float inv = 1.0f / lrow;
    float invq[4];
#pragma unroll
    for (int r = 0; r < 4; ++r) invq[r] = __shfl(inv, 4 * g + r);
    const size_t rowbase = (size_t)(bh * SS + qt * QB + w * 16);
#pragma unroll
    for (int dt = 0; dt < 4; ++dt)
#pragma unroll
        for (int r = 0; r < 4; ++r)
            Out[(rowbase + 4 * g + r) * DD + dt * 16 + l15] = Oacc[dt][r] * invq[r];
}

extern "C" void kernel_launch(void* const* d_in, const int* in_sizes, int n_in,
                              void* d_out, int out_size, void* d_ws, size_t ws_size,
                              hipStream_t stream) {
    const float* Q   = (const float*)d_in[0];
    const float* K   = (const float*)d_in[1];
    const float* V   = (const float*)d_in[2];
    const int* mask  = (const int*)d_in[5];
    float* out       = (float*)d_out;

    attn_kernel<<<dim3(BH, NQT), 256, 0, stream>>>(Q, K, V, mask, out);
}